// Round 7
// baseline (281.815 us; speedup 1.0000x reference)
//
#include <hip/hip_runtime.h>
#include <cstdint>

#define KK 16384
#define EE 256
#define MM 1792            // N*V
#define NKC 32             // K split chunks
#define LRELU_ALPHA 0.2f

typedef __bf16 bf16x8 __attribute__((ext_vector_type(8)));
typedef float f32x4 __attribute__((ext_vector_type(4)));

// Wp packed fragment tiles: [og 0..15][g 0..511][16o x 32k = 512 shorts]
#define OG_STR (512*512)
// ws: Wp 8 MB | part f32 [NKC][256][1792] 58.7 MB | Wh f32 [256][1792]
#define WP_BYTES (16u*OG_STR*2u)
#define PART_ELEMS ((size_t)NKC*256u*MM)

__device__ __forceinline__ unsigned short f2bf(float f){
  union { float f; unsigned u; } x; x.f = f;
  unsigned r = x.u + 0x7fffu + ((x.u >> 16) & 1u);
  return (unsigned short)(r >> 16);
}

// ---------- Kernel 1: W[16384][256] f32 -> Wp[og][g][16o x 32k] bf16 (RNE) ----------
__global__ __launch_bounds__(256) void k_pack_w(const float* __restrict__ W,
                                                unsigned short* __restrict__ Wp){
  __shared__ unsigned short Tw[256*136];
  const int tid = threadIdx.x;
  const int bk  = blockIdx.x;          // 128 k-rows per block
  const int k0  = bk*128;
  #pragma unroll
  for (int it = 0; it < 32; ++it){
    int j   = tid + it*256;
    int k_l = j >> 6;
    int o4  = j & 63;
    float4 v = *reinterpret_cast<const float4*>(W + (size_t)(k0 + k_l)*EE + o4*4);
    Tw[(o4*4+0)*136 + k_l] = f2bf(v.x);
    Tw[(o4*4+1)*136 + k_l] = f2bf(v.y);
    Tw[(o4*4+2)*136 + k_l] = f2bf(v.z);
    Tw[(o4*4+3)*136 + k_l] = f2bf(v.w);
  }
  __syncthreads();
  const int wv = tid >> 6, lane = tid & 63, col = lane & 15, quad = lane >> 4;
  #pragma unroll
  for (int i = 0; i < 16; ++i){
    int tidx = wv*16 + i;
    int og = tidx >> 2, kh_l = tidx & 3;
    bf16x8 v = *reinterpret_cast<const bf16x8*>(&Tw[(og*16 + col)*136 + kh_l*32 + quad*8]);
    *reinterpret_cast<bf16x8*>(Wp + (size_t)og*OG_STR + (size_t)(bk*4 + kh_l)*512
                               + col*32 + quad*8) = v;
  }
}

// ---------- Kernel 2: barrier-free LDS-free GEMM ----------
// D[o][m] = sum_k Wt[o][k] hf[m][k].  grid (28 mt, 32 kc), 256 thr = 4 waves.
// wave w: oh = w&1 (o 128*oh..+128, 8 og), mh = w>>1 (m-rows mt*64 + mh*32..+32, 2 mg).
// B-frags: 8 scalar stride-28B loads per lane direct from h (L1-served overlap).
__global__ __launch_bounds__(256, 3) void k_gemm(const float* __restrict__ h,
                                                 const unsigned short* __restrict__ Wp,
                                                 float* __restrict__ part){
  const int tid  = threadIdx.x;
  const int mt   = blockIdx.x;   // 0..27
  const int kc   = blockIdx.y;   // 0..31
  const int w    = tid >> 6;
  const int oh   = w & 1;
  const int mh   = w >> 1;
  const int lane = tid & 63;
  const int col  = lane & 15;
  const int quad = lane >> 4;

  // per-lane h bases for the 2 m-groups (m -> n,v)
  int bbase[2];
  #pragma unroll
  for (int j = 0; j < 2; ++j){
    int m = mt*64 + (mh*2 + j)*16 + col;
    int n = m / 7;
    int v = m - n*7;
    bbase[j] = n*114688 + v;         // + c*448 + t*7 later (float index)
  }

  const unsigned short* aptr = Wp + (size_t)(oh*8)*OG_STR + (size_t)(kc*16)*512
                               + col*32 + quad*8;

  f32x4 acc[8][2];
  #pragma unroll
  for (int i = 0; i < 8; ++i)
    #pragma unroll
    for (int j = 0; j < 2; ++j)
      acc[i][j] = (f32x4){0.f, 0.f, 0.f, 0.f};

  for (int kh = 0; kh < 16; ++kh){
    const int c  = kc*8 + (kh >> 1);
    const int tb = (kh & 1)*32 + quad*8;
    // B-frags: 2 mg x 8 scalar loads, round-half-up pack to bf16x8
    bf16x8 bf[2];
    #pragma unroll
    for (int j = 0; j < 2; ++j){
      const float* p = h + (size_t)(bbase[j] + c*448 + tb*7);
      unsigned u[8];
      #pragma unroll
      for (int jj = 0; jj < 8; ++jj){
        union { float f; unsigned u; } x; x.f = p[jj*7];
        u[jj] = x.u + 0x8000u;
      }
      int4 d;
      d.x = __builtin_amdgcn_perm(u[1], u[0], 0x07060302);
      d.y = __builtin_amdgcn_perm(u[3], u[2], 0x07060302);
      d.z = __builtin_amdgcn_perm(u[5], u[4], 0x07060302);
      d.w = __builtin_amdgcn_perm(u[7], u[6], 0x07060302);
      union { int4 i; bf16x8 b; } cvt; cvt.i = d;
      bf[j] = cvt.b;
    }
    // A-frags: 8 og, contiguous 16B/lane from packed Wp (L2-hot)
    bf16x8 af[8];
    #pragma unroll
    for (int i = 0; i < 8; ++i)
      af[i] = *reinterpret_cast<const bf16x8*>(aptr + (size_t)i*OG_STR + kh*512);
    #pragma unroll
    for (int i = 0; i < 8; ++i)
      #pragma unroll
      for (int j = 0; j < 2; ++j)
        acc[i][j] = __builtin_amdgcn_mfma_f32_16x16x32_bf16(af[i], bf[j], acc[i][j], 0, 0, 0);
  }

  // part[kc][o][m], m dense 0..1791 (no padding: 1792 = 28*64)
  #pragma unroll
  for (int i = 0; i < 8; ++i){
    #pragma unroll
    for (int r = 0; r < 4; ++r){
      int o = (oh*8 + i)*16 + quad*4 + r;
      size_t rowbase = ((size_t)(kc*256 + o))*MM + mt*64;
      #pragma unroll
      for (int j = 0; j < 2; ++j)
        part[rowbase + (mh*2 + j)*16 + col] = acc[i][j][r];
    }
  }
}

// ---------- Kernel 3: reduce partials over kc ----------
__global__ __launch_bounds__(256) void k_reduce(const float* __restrict__ part,
                                                float* __restrict__ Wh){
  const int m = blockIdx.x*256 + threadIdx.x;
  const int o = blockIdx.y;
  float s = 0.f;
  #pragma unroll 8
  for (int k = 0; k < NKC; ++k)
    s += part[((size_t)(k*256 + o))*MM + m];
  Wh[(size_t)o*MM + m] = s;
}

// ---------- Kernel 4: attention + elu ----------
__global__ __launch_bounds__(256) void k_attn(const float* __restrict__ Wh,
                                              const float* __restrict__ a,
                                              const float* __restrict__ Bp,
                                              float* __restrict__ out){
  const int n    = blockIdx.x;
  const int tid  = threadIdx.x;
  const int lane = tid & 63;
  const int wv   = tid >> 6;

  __shared__ float adjn[49];
  __shared__ float red1[4][7], red2[4][7];
  __shared__ float s1s[7], s2s[7];
  __shared__ float att0[49], att[49];

  if (tid == 0){
    float adj[49];
    float mn = 1e30f, mx = -1e30f;
    for (int i = 0; i < 7; ++i)
      for (int j = 0; j < 7; ++j){
        float x = Bp[i*7+j] + 1e-6f + (i == j ? 1.f : 0.f);
        adj[i*7+j] = x;
        mn = fminf(mn, x); mx = fmaxf(mx, x);
      }
    float inv = 1.f / (mx - mn);
    for (int i = 0; i < 49; ++i) adj[i] = (adj[i] - mn) * inv;
    float d12[7];
    for (int i = 0; i < 7; ++i){
      float s = 0.f;
      for (int j = 0; j < 7; ++j) s += adj[i*7+j];
      d12[i] = 1.f / sqrtf(s);
    }
    for (int i = 0; i < 7; ++i)
      for (int j = 0; j < 7; ++j)
        adjn[i*7+j] = d12[i] * adj[i*7+j] * d12[j];
  }

  float wh[7];
  #pragma unroll
  for (int v = 0; v < 7; ++v)
    wh[v] = Wh[(size_t)tid*MM + n*7 + v];

  const float a1 = a[tid];
  const float a2 = a[256 + tid];

  #pragma unroll
  for (int v = 0; v < 7; ++v){
    float x1 = wh[v]*a1;
    float x2 = wh[v]*a2;
    #pragma unroll
    for (int off = 32; off > 0; off >>= 1){
      x1 += __shfl_down(x1, off);
      x2 += __shfl_down(x2, off);
    }
    if (lane == 0){ red1[wv][v] = x1; red2[wv][v] = x2; }
  }
  __syncthreads();
  if (tid < 7){
    s1s[tid] = red1[0][tid]+red1[1][tid]+red1[2][tid]+red1[3][tid];
    s2s[tid] = red2[0][tid]+red2[1][tid]+red2[2][tid]+red2[3][tid];
  }
  __syncthreads();
  if (tid < 7){
    const int v = tid;
    float e[7]; float mx = -1e30f;
    #pragma unroll
    for (int u = 0; u < 7; ++u){
      float t = s1s[v] + s2s[u];
      t = t > 0.f ? t : LRELU_ALPHA*t;
      e[u] = t; mx = fmaxf(mx, t);
    }
    float sum = 0.f;
    #pragma unroll
    for (int u = 0; u < 7; ++u){ e[u] = expf(e[u]-mx); sum += e[u]; }
    float inv = 1.f/sum;
    #pragma unroll
    for (int u = 0; u < 7; ++u) att0[v*7+u] = e[u]*inv;
  }
  __syncthreads();
  if (tid < 7){
    const int v = tid;
    #pragma unroll
    for (int u = 0; u < 7; ++u){
      float s = 0.f;
      #pragma unroll
      for (int w7 = 0; w7 < 7; ++w7) s += adjn[v*7+w7]*att0[w7*7+u];
      att[v*7+u] = s;
    }
  }
  __syncthreads();
  #pragma unroll
  for (int v = 0; v < 7; ++v){
    float hp = 0.f;
    #pragma unroll
    for (int u = 0; u < 7; ++u) hp += att[v*7+u]*wh[u];
    float o = hp > 0.f ? hp : expm1f(hp);
    out[(size_t)(n*7+v)*256 + tid] = o;
  }
}

extern "C" void kernel_launch(void* const* d_in, const int* in_sizes, int n_in,
                              void* d_out, int out_size, void* d_ws, size_t ws_size,
                              hipStream_t stream){
  const float* h  = (const float*)d_in[0];
  const float* W  = (const float*)d_in[1];
  const float* a  = (const float*)d_in[2];
  const float* Bp = (const float*)d_in[3];
  float* out = (float*)d_out;
  char* ws = (char*)d_ws;

  unsigned short* Wp   = (unsigned short*)ws;
  float*          part = (float*)(ws + WP_BYTES);
  float*          Wh   = part + PART_ELEMS;

  k_pack_w<<<128, 256, 0, stream>>>(W, Wp);
  k_gemm<<<dim3(28, NKC), 256, 0, stream>>>(h, Wp, part);
  k_reduce<<<dim3(7, 256), 256, 0, stream>>>(part, Wh);
  k_attn<<<256, 256, 0, stream>>>(Wh, a, Bp, out);
}